// Round 3
// baseline (1855.236 us; speedup 1.0000x reference)
//
#include <hip/hip_runtime.h>
#include <hip/hip_bf16.h>

#define NROW 16384
#define DIM 128
#define HOUT 256
#define SPLIT 4

typedef float f32x4 __attribute__((ext_vector_type(4)));
typedef __bf16 bf16x8 __attribute__((ext_vector_type(8)));
typedef unsigned int u32;
typedef unsigned int u32x4 __attribute__((ext_vector_type(4)));

// ---------------- Kernel 1: features f32 [N][128] -> fT bf16 [128][N]; zero deg ----
__global__ void k_transpose(const float* __restrict__ f, short* __restrict__ fT,
                            float* __restrict__ deg) {
    __shared__ short tr[128][72];
    const int t = threadIdx.x;
    const int j0 = blockIdx.x * 64;
    if (blockIdx.x < 64) deg[blockIdx.x * 256 + t] = 0.f;   // zero 16384 floats
    for (int it = 0; it < 8; ++it) {
        int slot = t + 256 * it;
        int j = slot >> 5;          // 0..63
        int dq = slot & 31;         // d = dq*4
        f32x4 v = *reinterpret_cast<const f32x4*>(f + (size_t)(j0 + j) * DIM + dq * 4);
#pragma unroll
        for (int c = 0; c < 4; ++c) {
            __hip_bfloat16 h = __float2bfloat16(v[c]);
            tr[dq * 4 + c][j] = *reinterpret_cast<short*>(&h);
        }
    }
    __syncthreads();
    for (int it = 0; it < 4; ++it) {
        int slot = t + 256 * it;
        int d = slot >> 3;          // 0..127
        int c8 = slot & 7;          // 8-bf16 chunk
        int4 v = *reinterpret_cast<const int4*>(&tr[d][c8 * 8]);
        *reinterpret_cast<int4*>(fT + (size_t)d * NROW + j0 + c8 * 8) = v;
    }
}

// ---------------- Kernel 2: streaming MFMA GEMM, no LDS, explicit prefetch ----------
// Fragment layouts (verified passing in R1/R2):
//   A (16x32): lane holds row (lane&15), k = (lane>>4)*8 .. +8   (8 contiguous)
//   B (32x16): lane holds col (lane&15), k = (lane>>4)*8 .. +8
//   C (16x16): col = lane&15, row = (lane>>4)*4 + r
// Wave tile: 32 rows x 64 cols. Block: 64 rows x 128 cols (w = wr*2+wc... wr=w>>1).
// Grid: 256 row-blocks x SPLIT(4) = 1024 blocks = 4 blocks/CU, 16 waves/CU.
__device__ inline bf16x8 cvt_a(const int4& a, const int4& b, int& ds) {
    union { u32x4 u; bf16x8 f; } U;
    U.u.x = (a.x ? 0x3F80u : 0u) | (a.y ? 0x3F800000u : 0u);
    U.u.y = (a.z ? 0x3F80u : 0u) | (a.w ? 0x3F800000u : 0u);
    U.u.z = (b.x ? 0x3F80u : 0u) | (b.y ? 0x3F800000u : 0u);
    U.u.w = (b.z ? 0x3F80u : 0u) | (b.w ? 0x3F800000u : 0u);
    ds += a.x + a.y + a.z + a.w + b.x + b.y + b.z + b.w;
    return U.f;
}

struct Regs { int4 a0a, a0b, a1a, a1b; bf16x8 b[4]; };

__device__ inline void load_tile(Regs& R, const int* aptr0, const int* aptr1,
                                 const short* bptr, int ko) {
    R.a0a = *reinterpret_cast<const int4*>(aptr0 + ko);
    R.a0b = *reinterpret_cast<const int4*>(aptr0 + ko + 4);
    R.a1a = *reinterpret_cast<const int4*>(aptr1 + ko);
    R.a1b = *reinterpret_cast<const int4*>(aptr1 + ko + 4);
#pragma unroll
    for (int ci = 0; ci < 4; ++ci)
        R.b[ci] = *reinterpret_cast<const bf16x8*>(bptr + (size_t)ci * 16 * NROW + ko);
}

__device__ inline void compute_tile(Regs& R, f32x4 (&acc)[2][4], int (&dsum)[2]) {
    bf16x8 af0 = cvt_a(R.a0a, R.a0b, dsum[0]);
    bf16x8 af1 = cvt_a(R.a1a, R.a1b, dsum[1]);
#pragma unroll
    for (int ci = 0; ci < 4; ++ci) {
        acc[0][ci] = __builtin_amdgcn_mfma_f32_16x16x32_bf16(af0, R.b[ci], acc[0][ci], 0, 0, 0);
        acc[1][ci] = __builtin_amdgcn_mfma_f32_16x16x32_bf16(af1, R.b[ci], acc[1][ci], 0, 0, 0);
    }
}

__global__ __launch_bounds__(256, 4) void k_gemm(const int* __restrict__ adj,
                                                 const short* __restrict__ fT,
                                                 float* __restrict__ part,
                                                 float* __restrict__ deg) {
    const int t = threadIdx.x;
    const int rb = blockIdx.x >> 2;          // 0..255: 64-row block
    const int s  = blockIdx.x & 3;           // K quarter
    const int i0 = rb * 64;
    const int kb0 = s * (NROW / SPLIT);      // 4096-wide K slice
    const int lane = t & 63;
    const int w = t >> 6;
    const int wr = w >> 1;                   // row half (0..1)
    const int wc = w & 1;                    // col half (0..1)
    const int lr = lane & 15;
    const int lk = (lane >> 4) * 8;

    f32x4 acc[2][4] = {};
    int dsum[2] = {0, 0};

    const int* aptr0 = adj + (size_t)(i0 + wr * 32 + lr) * NROW + kb0 + lk;
    const int* aptr1 = aptr0 + (size_t)16 * NROW;
    const short* bptr = fT + (size_t)(wc * 64 + lr) * NROW + kb0 + lk;

    Regs R0, R1;
    load_tile(R0, aptr0, aptr1, bptr, 0);
#pragma unroll 1
    for (int it = 0; it < 128; it += 2) {     // 128 k-tiles of 32
        load_tile(R1, aptr0, aptr1, bptr, (it + 1) * 32);
        compute_tile(R0, acc, dsum);
        load_tile(R0, aptr0, aptr1, bptr, ((it + 2) & 127) * 32);  // wrap: last is dummy
        compute_tile(R1, acc, dsum);
    }
    // store partials
#pragma unroll
    for (int ti = 0; ti < 2; ++ti)
#pragma unroll
        for (int ci = 0; ci < 4; ++ci)
#pragma unroll
            for (int r = 0; r < 4; ++r) {
                int i = i0 + wr * 32 + ti * 16 + (lane >> 4) * 4 + r;
                int d = wc * 64 + ci * 16 + lr;
                part[((size_t)s * NROW + i) * DIM + d] = acc[ti][ci][r];
            }
    // deg: dsum is this lane's k-chunk sum for rows (wr*32+lr, +16); sum lane groups.
    if (wc == 0) {
#pragma unroll
        for (int ti = 0; ti < 2; ++ti) {
            float v = (float)dsum[ti];
            v += __shfl_xor(v, 16);
            v += __shfl_xor(v, 32);
            if (lane < 16) atomicAdd(deg + i0 + wr * 32 + ti * 16 + lr, v);
        }
    }
}

// ---------------- Kernel 3: epilogue (unchanged from R2) ----------------------------
__global__ __launch_bounds__(256, 2) void k_epilogue(const float* __restrict__ feat,
                                                     const float* __restrict__ part,
                                                     const float* __restrict__ deg,
                                                     const float* __restrict__ Wd,
                                                     const float* __restrict__ bd,
                                                     const float* __restrict__ Wo,
                                                     const float* __restrict__ bo,
                                                     float* __restrict__ out) {
    __shared__ float fs[32][132];
    __shared__ float tn[32][132];
    __shared__ float mrow[32], inv[32];
    const int t = threadIdx.x;
    const int i0 = blockIdx.x * 32;
    if (t < 32) {
        float d = deg[i0 + t];
        mrow[t] = d > 0.f ? 1.f : 0.f;
        inv[t]  = d > 0.f ? 1.f / d : 1.f;
    }
    __syncthreads();
    for (int it = 0; it < 4; ++it) {
        int slot = t + 256 * it;
        int r = slot >> 5, dq = slot & 31;
        size_t gi = (size_t)(i0 + r) * DIM + dq * 4;
        f32x4 fv = *reinterpret_cast<const f32x4*>(feat + gi);
        *reinterpret_cast<f32x4*>(&fs[r][dq * 4]) = fv;
        f32x4 p = *reinterpret_cast<const f32x4*>(part + gi);
#pragma unroll
        for (int sp = 1; sp < SPLIT; ++sp)
            p += *reinterpret_cast<const f32x4*>(part + (size_t)sp * NROW * DIM + gi);
        f32x4 tv = p * inv[r];
        *reinterpret_cast<f32x4*>(&tn[r][dq * 4]) = tv;
    }
    __syncthreads();
    const int rt = t & 7;   // rows rt*4..+4
    const int ht = t >> 3;  // h = ht*8..+8
    float accM[4][8] = {};  // f·Wo − tn·Wd2
    float accB[4][8] = {};  // f·Wd1
    for (int d = 0; d < DIM; d += 4) {
        f32x4 fr[4], tr[4];
#pragma unroll
        for (int rr = 0; rr < 4; ++rr) {
            fr[rr] = *reinterpret_cast<const f32x4*>(&fs[rt * 4 + rr][d]);
            tr[rr] = *reinterpret_cast<const f32x4*>(&tn[rt * 4 + rr][d]);
        }
#pragma unroll
        for (int hh = 0; hh < 8; ++hh) {
            int h = ht * 8 + hh;
            f32x4 wo = *reinterpret_cast<const f32x4*>(Wo + (size_t)h * DIM + d);
            f32x4 w1 = *reinterpret_cast<const f32x4*>(Wd + (size_t)h * 2 * DIM + d);
            f32x4 w2 = *reinterpret_cast<const f32x4*>(Wd + (size_t)h * 2 * DIM + DIM + d);
#pragma unroll
            for (int rr = 0; rr < 4; ++rr)
#pragma unroll
                for (int c = 0; c < 4; ++c) {
                    accM[rr][hh] += fr[rr][c] * wo[c] - tr[rr][c] * w2[c];
                    accB[rr][hh] += fr[rr][c] * w1[c];
                }
        }
    }
    f32x4 bo0 = *reinterpret_cast<const f32x4*>(bo + ht * 8);
    f32x4 bo1 = *reinterpret_cast<const f32x4*>(bo + ht * 8 + 4);
    f32x4 bd0 = *reinterpret_cast<const f32x4*>(bd + ht * 8);
    f32x4 bd1 = *reinterpret_cast<const f32x4*>(bd + ht * 8 + 4);
#pragma unroll
    for (int rr = 0; rr < 4; ++rr) {
        int i = i0 + rt * 4 + rr;
        float m = mrow[rt * 4 + rr];
        f32x4 v0, v1;
#pragma unroll
        for (int c = 0; c < 4; ++c) {
            v0[c] = tanhf(accM[rr][c]     - m * accB[rr][c]     + bo0[c] - bd0[c]);
            v1[c] = tanhf(accM[rr][c + 4] - m * accB[rr][c + 4] + bo1[c] - bd1[c]);
        }
        float* o = out + (size_t)i * HOUT + ht * 8;
        *reinterpret_cast<f32x4*>(o) = v0;
        *reinterpret_cast<f32x4*>(o + 4) = v1;
        float* o2 = o + (size_t)NROW * HOUT;
        *reinterpret_cast<f32x4*>(o2) = v0;
        *reinterpret_cast<f32x4*>(o2 + 4) = v1;
    }
}

extern "C" void kernel_launch(void* const* d_in, const int* in_sizes, int n_in,
                              void* d_out, int out_size, void* d_ws, size_t ws_size,
                              hipStream_t stream) {
    const float* feat = (const float*)d_in[0];
    const int*   adj  = (const int*)d_in[1];
    const float* Wd   = (const float*)d_in[2];
    const float* bd   = (const float*)d_in[3];
    const float* Wo   = (const float*)d_in[4];
    const float* bo   = (const float*)d_in[5];
    float* out = (float*)d_out;
    char* ws = (char*)d_ws;
    short* fT   = (short*)ws;                              //  4 MB: [128][16384] bf16
    float* part = (float*)(ws + (size_t)4  * 1024 * 1024); // 33.5 MB: [4][16384][128] f32
    float* deg  = (float*)(ws + (size_t)40 * 1024 * 1024); // 64 KB
    k_transpose<<<256,  256, 0, stream>>>(feat, fT, deg);
    k_gemm     <<<1024, 256, 0, stream>>>(adj, fT, part, deg);
    k_epilogue <<<512,  256, 0, stream>>>(feat, part, deg, Wd, bd, Wo, bo, out);
}

// Round 5
// 1604.341 us; speedup vs baseline: 1.1564x; 1.1564x over previous
//
#include <hip/hip_runtime.h>
#include <hip/hip_bf16.h>

#define NROW 16384
#define DIM 128
#define HOUT 256
#define SPLIT 4

typedef float f32x4 __attribute__((ext_vector_type(4)));
typedef __bf16 bf16x8 __attribute__((ext_vector_type(8)));
typedef int v4i __attribute__((ext_vector_type(4)));
typedef unsigned int u32;
typedef unsigned int u32x4 __attribute__((ext_vector_type(4)));

// ---------------- Kernel 1: features f32 [N][128] -> fT bf16 [128][N]; zero deg ----
__global__ void k_transpose(const float* __restrict__ f, short* __restrict__ fT,
                            float* __restrict__ deg) {
    __shared__ short tr[128][72];
    const int t = threadIdx.x;
    const int j0 = blockIdx.x * 64;
    if (blockIdx.x < 64) deg[blockIdx.x * 256 + t] = 0.f;   // zero 16384 floats
    for (int it = 0; it < 8; ++it) {
        int slot = t + 256 * it;
        int j = slot >> 5;          // 0..63
        int dq = slot & 31;         // d = dq*4
        f32x4 v = *reinterpret_cast<const f32x4*>(f + (size_t)(j0 + j) * DIM + dq * 4);
#pragma unroll
        for (int c = 0; c < 4; ++c) {
            __hip_bfloat16 h = __float2bfloat16(v[c]);
            tr[dq * 4 + c][j] = *reinterpret_cast<short*>(&h);
        }
    }
    __syncthreads();
    for (int it = 0; it < 4; ++it) {
        int slot = t + 256 * it;
        int d = slot >> 3;          // 0..127
        int c8 = slot & 7;          // 8-bf16 chunk
        int4 v = *reinterpret_cast<const int4*>(&tr[d][c8 * 8]);
        *reinterpret_cast<int4*>(fT + (size_t)d * NROW + j0 + c8 * 8) = v;
    }
}

// ---------------- Kernel 2: streaming MFMA GEMM, asm loads + vmcnt(0) dbuf ----------
// Fragment layouts (verified passing R1-R3):
//   A (16x32): lane holds row (lane&15), k = (lane>>4)*8 .. +8
//   B (32x16): lane holds col (lane&15), k = (lane>>4)*8 .. +8
//   C (16x16): col = lane&15, row = (lane>>4)*4 + r
// Wave tile: 32 rows x 128 cols (adj read exactly once; 4 waves' B-loads are identical
// addresses -> L1 broadcast). Block = 128 rows. Grid: 128 row-blocks x SPLIT(4) = 512
// blocks = 2 blocks/CU. Pipeline: issue 2 tiles (24 x4-loads) -> s_waitcnt vmcnt(0) +
// sched_barrier(0) [rule #18] -> compute both -> issue next pair. Named v4i asm outputs
// (no aggregates), SGPR bases + single VGPR offset per stream, pressure ~180 < 256 cap.
__device__ inline bf16x8 cvt8(v4i a, v4i b, int& ds) {
    union { u32x4 u; bf16x8 f; } U;
    U.u[0] = (a[0] ? 0x3F80u : 0u) | (a[1] ? 0x3F800000u : 0u);
    U.u[1] = (a[2] ? 0x3F80u : 0u) | (a[3] ? 0x3F800000u : 0u);
    U.u[2] = (b[0] ? 0x3F80u : 0u) | (b[1] ? 0x3F800000u : 0u);
    U.u[3] = (b[2] ? 0x3F80u : 0u) | (b[3] ? 0x3F800000u : 0u);
    ds += a[0] + a[1] + a[2] + a[3] + b[0] + b[1] + b[2] + b[3];
    return U.f;
}
__device__ inline bf16x8 as_bf(v4i v) { union { v4i i; bf16x8 f; } U; U.i = v; return U.f; }

#define GLD(dst, voff, base) \
    asm volatile("global_load_dwordx4 %0, %1, %2" : "=v"(dst) : "v"(voff), "s"(base))
#define GLD16(dst, voff, base) \
    asm volatile("global_load_dwordx4 %0, %1, %2 offset:16" : "=v"(dst) : "v"(voff), "s"(base))

__global__ __launch_bounds__(256, 2) void k_gemm(const int* __restrict__ adj,
                                                 const short* __restrict__ fT,
                                                 float* __restrict__ part,
                                                 float* __restrict__ deg) {
    const int t = threadIdx.x;
    const int rb = blockIdx.x >> 2;          // 0..127: 128-row block
    const int s  = blockIdx.x & 3;           // K quarter
    const int i0 = rb * 128;
    const int kb0 = s * (NROW / SPLIT);      // 4096-wide K slice
    const int lane = t & 63;
    const int w = t >> 6;                    // wave id: rows w*32..+32
    const int lr = lane & 15;
    const int lk = (lane >> 4) * 8;

    f32x4 acc[2][8] = {};
    int dsum0 = 0, dsum1 = 0;

    // SGPR bases (uniform), per-lane VGPR byte offsets
    const int*   adjLo = adj;
    const int*   adjHi = adj + (size_t)16 * NROW;
    const short* fT0 = fT;
    const short* fT1 = fT + (size_t)16 * NROW;
    const short* fT2 = fT + (size_t)32 * NROW;
    const short* fT3 = fT + (size_t)48 * NROW;
    const short* fT4 = fT + (size_t)64 * NROW;
    const short* fT5 = fT + (size_t)80 * NROW;
    const short* fT6 = fT + (size_t)96 * NROW;
    const short* fT7 = fT + (size_t)112 * NROW;
    u32 ofsA = (u32)((i0 + w * 32 + lr) * NROW + kb0 + lk) * 4u;
    u32 ofsB = (u32)(lr * NROW + kb0 + lk) * 2u;

    // tile buffers: named scalars only (no aggregates -> no SROA/scratch risk)
    v4i T0Aa, T0Ab, T0Ac, T0Ad, T0B0, T0B1, T0B2, T0B3, T0B4, T0B5, T0B6, T0B7;
    v4i T1Aa, T1Ab, T1Ac, T1Ad, T1B0, T1B1, T1B2, T1B3, T1B4, T1B5, T1B6, T1B7;

#define ISSUE(P)                                                        \
    do {                                                                \
        GLD  (P##Aa, ofsA, adjLo);  GLD16(P##Ab, ofsA, adjLo);          \
        GLD  (P##Ac, ofsA, adjHi);  GLD16(P##Ad, ofsA, adjHi);          \
        GLD(P##B0, ofsB, fT0);  GLD(P##B1, ofsB, fT1);                  \
        GLD(P##B2, ofsB, fT2);  GLD(P##B3, ofsB, fT3);                  \
        GLD(P##B4, ofsB, fT4);  GLD(P##B5, ofsB, fT5);                  \
        GLD(P##B6, ofsB, fT6);  GLD(P##B7, ofsB, fT7);                  \
        ofsA += 128u;  ofsB += 64u;                                     \
    } while (0)

#define WAIT0                                         \
    do {                                              \
        asm volatile("s_waitcnt vmcnt(0)");           \
        __builtin_amdgcn_sched_barrier(0);            \
    } while (0)

#define MM(P, ci)                                                                            \
    acc[0][ci] = __builtin_amdgcn_mfma_f32_16x16x32_bf16(af0, as_bf(P##B##ci), acc[0][ci], 0, 0, 0); \
    acc[1][ci] = __builtin_amdgcn_mfma_f32_16x16x32_bf16(af1, as_bf(P##B##ci), acc[1][ci], 0, 0, 0)

#define COMPUTE(P)                                    \
    do {                                              \
        bf16x8 af0 = cvt8(P##Aa, P##Ab, dsum0);       \
        bf16x8 af1 = cvt8(P##Ac, P##Ad, dsum1);       \
        MM(P, 0); MM(P, 1); MM(P, 2); MM(P, 3);       \
        MM(P, 4); MM(P, 5); MM(P, 6); MM(P, 7);       \
    } while (0)

    ISSUE(T0);          // tile 0
    ISSUE(T1);          // tile 1
#pragma unroll 1
    for (int it = 0; it < 126; it += 2) {    // computes tiles it, it+1; issues it+2, it+3
        WAIT0;
        COMPUTE(T0);
        COMPUTE(T1);
        ISSUE(T0);
        ISSUE(T1);
    }
    WAIT0;              // tail: tiles 126, 127 (nothing left in flight afterwards)
    COMPUTE(T0);
    COMPUTE(T1);

    // store partials: C layout col=lane&15, row=(lane>>4)*4+r
#pragma unroll
    for (int ti = 0; ti < 2; ++ti)
#pragma unroll
        for (int ci = 0; ci < 8; ++ci)
#pragma unroll
            for (int r = 0; r < 4; ++r) {
                int i = i0 + w * 32 + ti * 16 + (lane >> 4) * 4 + r;
                int d = ci * 16 + lr;
                part[((size_t)s * NROW + i) * DIM + d] = acc[ti][ci][r];
            }
    // deg: lanes {lr, lr+16, lr+32, lr+48} hold k-chunk sums of rows (w*32+lr, +16)
    {
        float v0 = (float)dsum0;
        v0 += __shfl_xor(v0, 16);
        v0 += __shfl_xor(v0, 32);
        float v1 = (float)dsum1;
        v1 += __shfl_xor(v1, 16);
        v1 += __shfl_xor(v1, 32);
        if (lane < 16) {
            atomicAdd(deg + i0 + w * 32 + lr, v0);
            atomicAdd(deg + i0 + w * 32 + 16 + lr, v1);
        }
    }
#undef ISSUE
#undef WAIT0
#undef MM
#undef COMPUTE
}

// ---------------- Kernel 3: epilogue (unchanged) ------------------------------------
__global__ __launch_bounds__(256, 2) void k_epilogue(const float* __restrict__ feat,
                                                     const float* __restrict__ part,
                                                     const float* __restrict__ deg,
                                                     const float* __restrict__ Wd,
                                                     const float* __restrict__ bd,
                                                     const float* __restrict__ Wo,
                                                     const float* __restrict__ bo,
                                                     float* __restrict__ out) {
    __shared__ float fs[32][132];
    __shared__ float tn[32][132];
    __shared__ float mrow[32], inv[32];
    const int t = threadIdx.x;
    const int i0 = blockIdx.x * 32;
    if (t < 32) {
        float d = deg[i0 + t];
        mrow[t] = d > 0.f ? 1.f : 0.f;
        inv[t]  = d > 0.f ? 1.f / d : 1.f;
    }
    __syncthreads();
    for (int it = 0; it < 4; ++it) {
        int slot = t + 256 * it;
        int r = slot >> 5, dq = slot & 31;
        size_t gi = (size_t)(i0 + r) * DIM + dq * 4;
        f32x4 fv = *reinterpret_cast<const f32x4*>(feat + gi);
        *reinterpret_cast<f32x4*>(&fs[r][dq * 4]) = fv;
        f32x4 p = *reinterpret_cast<const f32x4*>(part + gi);
#pragma unroll
        for (int sp = 1; sp < SPLIT; ++sp)
            p += *reinterpret_cast<const f32x4*>(part + (size_t)sp * NROW * DIM + gi);
        f32x4 tv = p * inv[r];
        *reinterpret_cast<f32x4*>(&tn[r][dq * 4]) = tv;
    }
    __syncthreads();
    const int rt = t & 7;   // rows rt*4..+4
    const int ht = t >> 3;  // h = ht*8..+8
    float accM[4][8] = {};  // f·Wo − tn·Wd2
    float accB[4][8] = {};  // f·Wd1
    for (int d = 0; d < DIM; d += 4) {
        f32x4 fr[4], tr[4];
#pragma unroll
        for (int rr = 0; rr < 4; ++rr) {
            fr[rr] = *reinterpret_cast<const f32x4*>(&fs[rt * 4 + rr][d]);
            tr[rr] = *reinterpret_cast<const f32x4*>(&tn[rt * 4 + rr][d]);
        }
#pragma unroll
        for (int hh = 0; hh < 8; ++hh) {
            int h = ht * 8 + hh;
            f32x4 wo = *reinterpret_cast<const f32x4*>(Wo + (size_t)h * DIM + d);
            f32x4 w1 = *reinterpret_cast<const f32x4*>(Wd + (size_t)h * 2 * DIM + d);
            f32x4 w2 = *reinterpret_cast<const f32x4*>(Wd + (size_t)h * 2 * DIM + DIM + d);
#pragma unroll
            for (int rr = 0; rr < 4; ++rr)
#pragma unroll
                for (int c = 0; c < 4; ++c) {
                    accM[rr][hh] += fr[rr][c] * wo[c] - tr[rr][c] * w2[c];
                    accB[rr][hh] += fr[rr][c] * w1[c];
                }
        }
    }
    f32x4 bo0 = *reinterpret_cast<const f32x4*>(bo + ht * 8);
    f32x4 bo1 = *reinterpret_cast<const f32x4*>(bo + ht * 8 + 4);
    f32x4 bd0 = *reinterpret_cast<const f32x4*>(bd + ht * 8);
    f32x4 bd1 = *reinterpret_cast<const f32x4*>(bd + ht * 8 + 4);
#pragma unroll
    for (int rr = 0; rr < 4; ++rr) {
        int i = i0 + rt * 4 + rr;
        float m = mrow[rt * 4 + rr];
        f32x4 v0, v1;
#pragma unroll
        for (int c = 0; c < 4; ++c) {
            v0[c] = tanhf(accM[rr][c]     - m * accB[rr][c]     + bo0[c] - bd0[c]);
            v1[c] = tanhf(accM[rr][c + 4] - m * accB[rr][c + 4] + bo1[c] - bd1[c]);
        }
        float* o = out + (size_t)i * HOUT + ht * 8;
        *reinterpret_cast<f32x4*>(o) = v0;
        *reinterpret_cast<f32x4*>(o + 4) = v1;
        float* o2 = o + (size_t)NROW * HOUT;
        *reinterpret_cast<f32x4*>(o2) = v0;
        *reinterpret_cast<f32x4*>(o2 + 4) = v1;
    }
}

extern "C" void kernel_launch(void* const* d_in, const int* in_sizes, int n_in,
                              void* d_out, int out_size, void* d_ws, size_t ws_size,
                              hipStream_t stream) {
    const float* feat = (const float*)d_in[0];
    const int*   adj  = (const int*)d_in[1];
    const float* Wd   = (const float*)d_in[2];
    const float* bd   = (const float*)d_in[3];
    const float* Wo   = (const float*)d_in[4];
    const float* bo   = (const float*)d_in[5];
    float* out = (float*)d_out;
    char* ws = (char*)d_ws;
    short* fT   = (short*)ws;                              //  4 MB: [128][16384] bf16
    float* part = (float*)(ws + (size_t)4  * 1024 * 1024); // 33.5 MB: [4][16384][128] f32
    float* deg  = (float*)(ws + (size_t)40 * 1024 * 1024); // 64 KB
    k_transpose<<<256, 256, 0, stream>>>(feat, fT, deg);
    k_gemm     <<<512, 256, 0, stream>>>(adj, fT, part, deg);
    k_epilogue <<<512, 256, 0, stream>>>(feat, part, deg, Wd, bd, Wo, bo, out);
}

// Round 6
// 1431.092 us; speedup vs baseline: 1.2964x; 1.1211x over previous
//
#include <hip/hip_runtime.h>
#include <hip/hip_bf16.h>

#define NROW 16384
#define DIM 128
#define HOUT 256
#define SPLIT 4

typedef float f32x4 __attribute__((ext_vector_type(4)));
typedef __bf16 bf16x8 __attribute__((ext_vector_type(8)));
typedef int v4i __attribute__((ext_vector_type(4)));
typedef unsigned int u32;
typedef unsigned int u32x4 __attribute__((ext_vector_type(4)));

// ---------------- Kernel 1: features f32 [N][128] -> fT bf16 [128][N]; zero deg ----
__global__ void k_transpose(const float* __restrict__ f, short* __restrict__ fT,
                            float* __restrict__ deg) {
    __shared__ short tr[128][72];
    const int t = threadIdx.x;
    const int j0 = blockIdx.x * 64;
    if (blockIdx.x < 64) deg[blockIdx.x * 256 + t] = 0.f;   // zero 16384 floats
    for (int it = 0; it < 8; ++it) {
        int slot = t + 256 * it;
        int j = slot >> 5;          // 0..63
        int dq = slot & 31;         // d = dq*4
        f32x4 v = *reinterpret_cast<const f32x4*>(f + (size_t)(j0 + j) * DIM + dq * 4);
#pragma unroll
        for (int c = 0; c < 4; ++c) {
            __hip_bfloat16 h = __float2bfloat16(v[c]);
            tr[dq * 4 + c][j] = *reinterpret_cast<short*>(&h);
        }
    }
    __syncthreads();
    for (int it = 0; it < 4; ++it) {
        int slot = t + 256 * it;
        int d = slot >> 3;          // 0..127
        int c8 = slot & 7;          // 8-bf16 chunk
        int4 v = *reinterpret_cast<const int4*>(&tr[d][c8 * 8]);
        *reinterpret_cast<int4*>(fT + (size_t)d * NROW + j0 + c8 * 8) = v;
    }
}

// ---------------- Kernel 2: m97-structure GEMM via global_load_lds ------------------
// Block: 128 rows x 128 d x K_STEP=32, double-buffered LDS (48 KB), 4 waves.
// Per step: issue 6 global_load_lds (16B) for tile t+1; ds_read+cvt+16 MFMA on tile t;
// one __syncthreads (drains vmcnt+lgkmcnt per HIP semantics). Staging uses ZERO VGPRs
// -> no register-allocator fights (R3/R5 lesson). fT staged once per BLOCK (was per
// wave). Grid: 128 row-blocks x SPLIT(4) = 512 = 2 blocks/CU.
// Fragment layouts (verified passing R1-R5):
//   A (16x32): lane holds row (lane&15), k = (lane>>4)*8 .. +8
//   B (32x16): lane holds col (lane&15), k = (lane>>4)*8 .. +8
//   C (16x16): col = lane&15, row = (lane>>4)*4 + r
__device__ inline bf16x8 cvt8(v4i a, v4i b, int& ds) {
    union { u32x4 u; bf16x8 f; } U;
    U.u[0] = (a[0] ? 0x3F80u : 0u) | (a[1] ? 0x3F800000u : 0u);
    U.u[1] = (a[2] ? 0x3F80u : 0u) | (a[3] ? 0x3F800000u : 0u);
    U.u[2] = (b[0] ? 0x3F80u : 0u) | (b[1] ? 0x3F800000u : 0u);
    U.u[3] = (b[2] ? 0x3F80u : 0u) | (b[3] ? 0x3F800000u : 0u);
    ds += a[0] + a[1] + a[2] + a[3] + b[0] + b[1] + b[2] + b[3];
    return U.f;
}

#define GLOAD16(g, l)                                                         \
    __builtin_amdgcn_global_load_lds(                                         \
        (const __attribute__((address_space(1))) unsigned int*)(g),           \
        (__attribute__((address_space(3))) unsigned int*)(l), 16, 0, 0)

__global__ __launch_bounds__(256, 2) void k_gemm(const int* __restrict__ adj,
                                                 const short* __restrict__ fT,
                                                 float* __restrict__ part,
                                                 float* __restrict__ deg) {
    __shared__ int   As[2][128][32];   // 2 x 16 KB
    __shared__ short Fs[2][128][32];   // 2 x  8 KB
    const int t = threadIdx.x;
    const int rb = blockIdx.x >> 2;          // 0..127: 128-row block
    const int s  = blockIdx.x & 3;           // K quarter
    const int i0 = rb * 128;
    const int kb0 = s * (NROW / SPLIT);      // 4096-wide K slice
    const int lane = t & 63;
    const int w = t >> 6;                    // wave id (uniform per wave)
    const int lr = lane & 15;
    const int lk8 = lane >> 4;               // k-phase 0..3, k0 = lk8*8

    f32x4 acc[2][8] = {};
    int dsum0 = 0, dsum1 = 0;

    // Staging: adj slots 0..1023 (row=slot>>3, kq=slot&7, 16B each), LDS byte = slot*16
    //          fT  slots 0..511  (d=slot>>2,  c8=slot&3, 16B each), LDS byte = slot*16
    // Per wave+round the LDS base is uniform; global addr is per-lane. (m104 semantics)
#define STAGE(cur, kb)                                                            \
    do {                                                                          \
        _Pragma("unroll")                                                         \
        for (int r = 0; r < 4; ++r) {                                             \
            int uslot = r * 256 + w * 64;                                         \
            int slot = uslot + lane;                                              \
            const int* g = adj + (size_t)(i0 + (slot >> 3)) * NROW + (kb) + (slot & 7) * 4; \
            GLOAD16(g, (char*)&As[cur][0][0] + (size_t)uslot * 16);               \
        }                                                                         \
        _Pragma("unroll")                                                         \
        for (int r = 0; r < 2; ++r) {                                             \
            int uslot = r * 256 + w * 64;                                         \
            int slot = uslot + lane;                                              \
            const short* g = fT + (size_t)(slot >> 2) * NROW + (kb) + (slot & 3) * 8; \
            GLOAD16(g, (char*)&Fs[cur][0][0] + (size_t)uslot * 16);               \
        }                                                                         \
    } while (0)

    STAGE(0, kb0);
    __syncthreads();                         // drains vmcnt (HIP barrier semantics)

    int cur = 0;
#pragma unroll 1
    for (int step = 0; step < 128; ++step) {
        if (step + 1 < 128) STAGE(cur ^ 1, kb0 + (step + 1) * 32);  // in flight over compute
        // consume tile cur
        bf16x8 bfr[8];
#pragma unroll
        for (int ci = 0; ci < 8; ++ci)
            bfr[ci] = *reinterpret_cast<const bf16x8*>(&Fs[cur][ci * 16 + lr][lk8 * 8]);
        v4i a0 = *reinterpret_cast<const v4i*>(&As[cur][w * 32 + lr][lk8 * 8]);
        v4i a1 = *reinterpret_cast<const v4i*>(&As[cur][w * 32 + lr][lk8 * 8 + 4]);
        v4i a2 = *reinterpret_cast<const v4i*>(&As[cur][w * 32 + 16 + lr][lk8 * 8]);
        v4i a3 = *reinterpret_cast<const v4i*>(&As[cur][w * 32 + 16 + lr][lk8 * 8 + 4]);
        bf16x8 af0 = cvt8(a0, a1, dsum0);
        bf16x8 af1 = cvt8(a2, a3, dsum1);
#pragma unroll
        for (int ci = 0; ci < 8; ++ci) {
            acc[0][ci] = __builtin_amdgcn_mfma_f32_16x16x32_bf16(af0, bfr[ci], acc[0][ci], 0, 0, 0);
            acc[1][ci] = __builtin_amdgcn_mfma_f32_16x16x32_bf16(af1, bfr[ci], acc[1][ci], 0, 0, 0);
        }
        __syncthreads();                     // next-tile loads landed; reads done
        cur ^= 1;
    }

    // store partials: C layout col=lane&15, row=(lane>>4)*4+r
#pragma unroll
    for (int ti = 0; ti < 2; ++ti)
#pragma unroll
        for (int ci = 0; ci < 8; ++ci)
#pragma unroll
            for (int r = 0; r < 4; ++r) {
                int i = i0 + w * 32 + ti * 16 + (lane >> 4) * 4 + r;
                int d = ci * 16 + lr;
                part[((size_t)s * NROW + i) * DIM + d] = acc[ti][ci][r];
            }
    // deg: lanes {lr, lr+16, lr+32, lr+48} hold k-phase sums of rows (w*32+lr, +16)
    {
        float v0 = (float)dsum0;
        v0 += __shfl_xor(v0, 16);
        v0 += __shfl_xor(v0, 32);
        float v1 = (float)dsum1;
        v1 += __shfl_xor(v1, 16);
        v1 += __shfl_xor(v1, 32);
        if (lane < 16) {
            atomicAdd(deg + i0 + w * 32 + lr, v0);
            atomicAdd(deg + i0 + w * 32 + 16 + lr, v1);
        }
    }
#undef STAGE
}

// ---------------- Kernel 3: epilogue (unchanged) ------------------------------------
__global__ __launch_bounds__(256, 2) void k_epilogue(const float* __restrict__ feat,
                                                     const float* __restrict__ part,
                                                     const float* __restrict__ deg,
                                                     const float* __restrict__ Wd,
                                                     const float* __restrict__ bd,
                                                     const float* __restrict__ Wo,
                                                     const float* __restrict__ bo,
                                                     float* __restrict__ out) {
    __shared__ float fs[32][132];
    __shared__ float tn[32][132];
    __shared__ float mrow[32], inv[32];
    const int t = threadIdx.x;
    const int i0 = blockIdx.x * 32;
    if (t < 32) {
        float d = deg[i0 + t];
        mrow[t] = d > 0.f ? 1.f : 0.f;
        inv[t]  = d > 0.f ? 1.f / d : 1.f;
    }
    __syncthreads();
    for (int it = 0; it < 4; ++it) {
        int slot = t + 256 * it;
        int r = slot >> 5, dq = slot & 31;
        size_t gi = (size_t)(i0 + r) * DIM + dq * 4;
        f32x4 fv = *reinterpret_cast<const f32x4*>(feat + gi);
        *reinterpret_cast<f32x4*>(&fs[r][dq * 4]) = fv;
        f32x4 p = *reinterpret_cast<const f32x4*>(part + gi);
#pragma unroll
        for (int sp = 1; sp < SPLIT; ++sp)
            p += *reinterpret_cast<const f32x4*>(part + (size_t)sp * NROW * DIM + gi);
        f32x4 tv = p * inv[r];
        *reinterpret_cast<f32x4*>(&tn[r][dq * 4]) = tv;
    }
    __syncthreads();
    const int rt = t & 7;   // rows rt*4..+4
    const int ht = t >> 3;  // h = ht*8..+8
    float accM[4][8] = {};  // f·Wo − tn·Wd2
    float accB[4][8] = {};  // f·Wd1
    for (int d = 0; d < DIM; d += 4) {
        f32x4 fr[4], tr[4];
#pragma unroll
        for (int rr = 0; rr < 4; ++rr) {
            fr[rr] = *reinterpret_cast<const f32x4*>(&fs[rt * 4 + rr][d]);
            tr[rr] = *reinterpret_cast<const f32x4*>(&tn[rt * 4 + rr][d]);
        }
#pragma unroll
        for (int hh = 0; hh < 8; ++hh) {
            int h = ht * 8 + hh;
            f32x4 wo = *reinterpret_cast<const f32x4*>(Wo + (size_t)h * DIM + d);
            f32x4 w1 = *reinterpret_cast<const f32x4*>(Wd + (size_t)h * 2 * DIM + d);
            f32x4 w2 = *reinterpret_cast<const f32x4*>(Wd + (size_t)h * 2 * DIM + DIM + d);
#pragma unroll
            for (int rr = 0; rr < 4; ++rr)
#pragma unroll
                for (int c = 0; c < 4; ++c) {
                    accM[rr][hh] += fr[rr][c] * wo[c] - tr[rr][c] * w2[c];
                    accB[rr][hh] += fr[rr][c] * w1[c];
                }
        }
    }
    f32x4 bo0 = *reinterpret_cast<const f32x4*>(bo + ht * 8);
    f32x4 bo1 = *reinterpret_cast<const f32x4*>(bo + ht * 8 + 4);
    f32x4 bd0 = *reinterpret_cast<const f32x4*>(bd + ht * 8);
    f32x4 bd1 = *reinterpret_cast<const f32x4*>(bd + ht * 8 + 4);
#pragma unroll
    for (int rr = 0; rr < 4; ++rr) {
        int i = i0 + rt * 4 + rr;
        float m = mrow[rt * 4 + rr];
        f32x4 v0, v1;
#pragma unroll
        for (int c = 0; c < 4; ++c) {
            v0[c] = tanhf(accM[rr][c]     - m * accB[rr][c]     + bo0[c] - bd0[c]);
            v1[c] = tanhf(accM[rr][c + 4] - m * accB[rr][c + 4] + bo1[c] - bd1[c]);
        }
        float* o = out + (size_t)i * HOUT + ht * 8;
        *reinterpret_cast<f32x4*>(o) = v0;
        *reinterpret_cast<f32x4*>(o + 4) = v1;
        float* o2 = o + (size_t)NROW * HOUT;
        *reinterpret_cast<f32x4*>(o2) = v0;
        *reinterpret_cast<f32x4*>(o2 + 4) = v1;
    }
}

extern "C" void kernel_launch(void* const* d_in, const int* in_sizes, int n_in,
                              void* d_out, int out_size, void* d_ws, size_t ws_size,
                              hipStream_t stream) {
    const float* feat = (const float*)d_in[0];
    const int*   adj  = (const int*)d_in[1];
    const float* Wd   = (const float*)d_in[2];
    const float* bd   = (const float*)d_in[3];
    const float* Wo   = (const float*)d_in[4];
    const float* bo   = (const float*)d_in[5];
    float* out = (float*)d_out;
    char* ws = (char*)d_ws;
    short* fT   = (short*)ws;                              //  4 MB: [128][16384] bf16
    float* part = (float*)(ws + (size_t)4  * 1024 * 1024); // 33.5 MB: [4][16384][128] f32
    float* deg  = (float*)(ws + (size_t)40 * 1024 * 1024); // 64 KB
    k_transpose<<<256, 256, 0, stream>>>(feat, fT, deg);
    k_gemm     <<<512, 256, 0, stream>>>(adj, fT, part, deg);
    k_epilogue <<<512, 256, 0, stream>>>(feat, part, deg, Wd, bd, Wo, bo, out);
}